// Round 1
// baseline (668.406 us; speedup 1.0000x reference)
//
#include <hip/hip_runtime.h>
#include <hip/hip_bf16.h>
#include <math.h>

// Problem constants (B=2048, D=512, C=100000)
constexpr int Bq = 2048;
constexpr int Dq = 512;
constexpr int Cq = 100000;
constexpr int NPAD = 100096;     // 782 * 128 (N padded to tile multiple)

constexpr float SCALE = 64.0f;
constexpr float COS_M = 0.8775825618903728f;   // cos(0.5)
constexpr float SIN_M = 0.479425538604203f;    // sin(0.5)
constexpr float THR   = -0.8775825618903728f;  // cos(pi - 0.5)
constexpr float MM    = 0.2397127693021015f;   // sin(pi - 0.5) * 0.5

typedef __attribute__((ext_vector_type(8))) __bf16 bf16x8;
typedef __attribute__((ext_vector_type(4))) float f32x4;

typedef const __attribute__((address_space(1))) unsigned int guint;
typedef __attribute__((address_space(3))) unsigned int suint;

__device__ __forceinline__ void gload_lds16(const unsigned short* g, unsigned short* lds)
{
    // width=16B direct global->LDS; LDS dest is wave-uniform base + lane*16
    __builtin_amdgcn_global_load_lds((guint*)g, (suint*)lds, 16, 0, 0);
}

// ---------------------------------------------------------------------------
// Row L2-normalize fp32 [nrows][512] -> bf16 [gridDim.x][512] (pad rows -> 0)
// 256 threads/block, 2 elements/thread.
// ---------------------------------------------------------------------------
__global__ __launch_bounds__(256) void normalize_rows_kernel(
    const float* __restrict__ in, unsigned short* __restrict__ out, int nrows)
{
    const int row = blockIdx.x;
    const int t = threadIdx.x;
    unsigned int* out32 = (unsigned int*)out;
    if (row >= nrows) {
        out32[(size_t)row * (Dq / 2) + t] = 0u;   // zero pad rows
        return;
    }
    float2 v = reinterpret_cast<const float2*>(in + (size_t)row * Dq)[t];
    float ss = v.x * v.x + v.y * v.y;
    #pragma unroll
    for (int off = 32; off > 0; off >>= 1) ss += __shfl_down(ss, off);
    __shared__ float wsum[4];
    const int wave = t >> 6, lane = t & 63;
    if (lane == 0) wsum[wave] = ss;
    __syncthreads();
    const float total = wsum[0] + wsum[1] + wsum[2] + wsum[3];
    const float invn = 1.0f / fmaxf(sqrtf(total), 1e-12f);
    __hip_bfloat16 h0 = __float2bfloat16(v.x * invn);
    __hip_bfloat16 h1 = __float2bfloat16(v.y * invn);
    unsigned int packed = ((unsigned int)(*(unsigned short*)&h1) << 16) |
                          (unsigned int)(*(unsigned short*)&h0);
    out32[(size_t)row * (Dq / 2) + t] = packed;
}

// ---------------------------------------------------------------------------
// GEMM: A[2048][512] bf16  x  Bn[NPAD][512] bf16 (row = class, B^T layout)
//   -> out[2048][100000] fp32, with ArcFace margin epilogue on target column.
// 128x128 tile, BK=64, 4 waves (2x2), mfma_f32_16x16x32_bf16, m97 structure.
// ---------------------------------------------------------------------------
__global__ __launch_bounds__(256) void arc_gemm_kernel(
    const unsigned short* __restrict__ A,
    const unsigned short* __restrict__ Bn,
    const int* __restrict__ labels,
    float* __restrict__ out)
{
    constexpr int BM = 128, BN = 128, BK = 64;
    __shared__ unsigned short As[BM * BK];   // [128][64] linear
    __shared__ unsigned short Bs[BN * BK];

    const int bid = blockIdx.x;
    const int tm = bid & 15;        // m-tile fastest -> 16 consecutive blocks
    const int tn = bid >> 4;        //   share one B strip (L2 reuse)
    const int m0 = tm * BM;
    const int n0 = tn * BN;

    const int t = threadIdx.x;
    const int wave = t >> 6;
    const int lane = t & 63;
    const int wr = (wave >> 1) * 64;   // wave origin within tile
    const int wc = (wave & 1) * 64;

    // staging coords: issue s covers tile rows [s*32, s*32+32); this thread
    // loads 16B at row = s*32 + t/8, col = (t&7)*8 elements
    const int srow = t >> 3;
    const int scol = (t & 7) * 8;
    const unsigned short* gA = A + (size_t)(m0 + srow) * Dq + scol;
    const unsigned short* gB = Bn + (size_t)(n0 + srow) * Dq + scol;
    unsigned short* lA = As + wave * 512;   // wave-uniform LDS base (bytes: wave*1024)
    unsigned short* lB = Bs + wave * 512;

    f32x4 acc[4][4];
    #pragma unroll
    for (int i = 0; i < 4; ++i)
        #pragma unroll
        for (int j = 0; j < 4; ++j) acc[i][j] = {0.f, 0.f, 0.f, 0.f};

    const int fr = lane & 15;   // fragment row (A) / col (B,D)
    const int kg = lane >> 4;   // k-group

    for (int kt = 0; kt < Dq / BK; ++kt) {
        #pragma unroll
        for (int s = 0; s < 4; ++s) {
            gload_lds16(gA + (size_t)(s * 32) * Dq + kt * BK, lA + s * 2048);
            gload_lds16(gB + (size_t)(s * 32) * Dq + kt * BK, lB + s * 2048);
        }
        __syncthreads();   // drains vmcnt(0) -> LDS tiles ready
        #pragma unroll
        for (int ks = 0; ks < 2; ++ks) {
            bf16x8 af[4], bf[4];
            #pragma unroll
            for (int mi = 0; mi < 4; ++mi)
                af[mi] = *reinterpret_cast<const bf16x8*>(
                    &As[(wr + mi * 16 + fr) * BK + ks * 32 + kg * 8]);
            #pragma unroll
            for (int ni = 0; ni < 4; ++ni)
                bf[ni] = *reinterpret_cast<const bf16x8*>(
                    &Bs[(wc + ni * 16 + fr) * BK + ks * 32 + kg * 8]);
            #pragma unroll
            for (int mi = 0; mi < 4; ++mi)
                #pragma unroll
                for (int ni = 0; ni < 4; ++ni)
                    acc[mi][ni] = __builtin_amdgcn_mfma_f32_16x16x32_bf16(
                        af[mi], bf[ni], acc[mi][ni], 0, 0, 0);
        }
        __syncthreads();   // all waves done reading before restaging
    }

    // Epilogue: D mapping col = lane&15, row = 4*(lane>>4) + reg
    const int rbase0 = m0 + wr + (lane >> 4) * 4;
    #pragma unroll
    for (int mi = 0; mi < 4; ++mi) {
        const int rbase = rbase0 + mi * 16;
        int labs[4];
        #pragma unroll
        for (int r = 0; r < 4; ++r) labs[r] = labels[rbase + r];
        #pragma unroll
        for (int ni = 0; ni < 4; ++ni) {
            const int gcol = n0 + wc + ni * 16 + fr;
            if (gcol >= Cq) continue;   // N tail guard
            f32x4 v = acc[mi][ni];
            #pragma unroll
            for (int r = 0; r < 4; ++r) {
                float c = v[r];
                float val = c;
                if (gcol == labs[r]) {   // rare: wave-uniform skip almost always
                    float sine = sqrtf(fmaxf(1.0f - c * c, 0.0f));
                    float phi = c * COS_M - sine * SIN_M;
                    val = (c > THR) ? phi : (c - MM);
                }
                out[(size_t)(rbase + r) * Cq + gcol] = val * SCALE;
            }
        }
    }
}

extern "C" void kernel_launch(void* const* d_in, const int* in_sizes, int n_in,
                              void* d_out, int out_size, void* d_ws, size_t ws_size,
                              hipStream_t stream)
{
    const float* emb    = (const float*)d_in[0];
    const int*   labels = (const int*)d_in[1];
    const float* weight = (const float*)d_in[2];
    float* out = (float*)d_out;

    unsigned short* Abf = (unsigned short*)d_ws;             // 2048*512 bf16 = 2 MB
    unsigned short* Bbf = Abf + (size_t)Bq * Dq;             // NPAD*512 bf16 = 102.5 MB

    normalize_rows_kernel<<<Bq, 256, 0, stream>>>(emb, Abf, Bq);
    normalize_rows_kernel<<<NPAD, 256, 0, stream>>>(weight, Bbf, Cq);
    arc_gemm_kernel<<<16 * (NPAD / 128), 256, 0, stream>>>(Abf, Bbf, labels, out);
}